// Round 1
// 725.768 us; speedup vs baseline: 1.3443x; 1.3443x over previous
//
#include <hip/hip_runtime.h>

// GQA group-attention: q/k/v GEMMs (bf16 MFMA) + per-token 16x16 group attention.
// R1: (a) GEMM -> 256x256 tile, BK=32, 4-deep circular LDS pipeline with counted
//     vmcnt(8) + raw s_barrier (never drains to 0 in steady state), setprio around
//     MFMA cluster, XCD-bijective block swizzle.
//     (b) attn -> one wave per token, K/V staged to private LDS region via
//     global_load_lds (no barriers), lane=(group g, quarter s), shfl_xor reduce.

#define DIM 2048
#define NTOT 6144   // 3*DIM, concatenated q|k|v per token
#define DG 128      // per-group dim
#define NG 16       // groups
#define BK 32
#define KTILES (DIM / BK)   // 64

typedef __bf16 bf16x8 __attribute__((ext_vector_type(8)));
typedef float f32x4 __attribute__((ext_vector_type(4)));
typedef unsigned short u16;
typedef unsigned int u32;

__device__ __forceinline__ u16 f2bf(float f) {
  u32 u = __float_as_uint(f);
  u = (u + 0x7fffu + ((u >> 16) & 1u)) >> 16;  // RNE
  return (u16)u;
}

__device__ __forceinline__ void gload16(const __bf16* g, __bf16* l) {
  // async global->LDS DMA, 16B per lane; LDS dest = wave-uniform base + lane*16,
  // global src is per-lane.
  __builtin_amdgcn_global_load_lds(
      (__attribute__((address_space(1))) void*)(void*)g,
      (__attribute__((address_space(3))) void*)l, 16, 0, 0);
}

__global__ __launch_bounds__(256) void cvt_kernel(const float* __restrict__ src,
                                                  u16* __restrict__ dst, int n4) {
  int i = blockIdx.x * 256 + threadIdx.x;
  if (i >= n4) return;
  float4 f = ((const float4*)src)[i];
  ushort4 o;
  o.x = f2bf(f.x); o.y = f2bf(f.y); o.z = f2bf(f.z); o.w = f2bf(f.w);
  ((ushort4*)dst)[i] = o;
}

__global__ __launch_bounds__(256) void cvtW_kernel(const float* __restrict__ wq,
                                                   const float* __restrict__ wk,
                                                   const float* __restrict__ wv,
                                                   u16* __restrict__ dst, int n4each) {
  int m = blockIdx.y;
  const float* s = (m == 0) ? wq : (m == 1) ? wk : wv;
  int i = blockIdx.x * 256 + threadIdx.x;
  if (i >= n4each) return;
  float4 f = ((const float4*)s)[i];
  ushort4 o;
  o.x = f2bf(f.x); o.y = f2bf(f.y); o.z = f2bf(f.z); o.w = f2bf(f.w);
  ((ushort4*)dst)[(size_t)m * n4each + i] = o;
}

// C[row][col] = A[row][:] . W[col][:] + bias, stored bf16.
// A: [M][2048] bf16, W: [6144][2048] bf16 (Wq|Wk|Wv rows), C: [M][6144] bf16.
// 256x256 tile, 8 waves (2x4), per-wave 128x64 output (acc[8][4]).
// LDS: 4 circular buffers x (A 16KB + B 16KB) = 128 KB.
__global__ __launch_bounds__(512, 1) void gemm_qkv(const __bf16* __restrict__ A,
                                                   const __bf16* __restrict__ W,
                                                   const float* __restrict__ bq,
                                                   const float* __restrict__ bk,
                                                   const float* __restrict__ bv,
                                                   u16* __restrict__ C) {
  __shared__ __bf16 lds[4 * 16384];  // 128 KB: buf q at q*16384, A then B(+8192)

  const int tid = threadIdx.x;       // 0..511
  const int lane = tid & 63;
  const int w = tid >> 6;            // wave 0..7
  const int wm = w >> 2, wn = w & 3; // 2 x 4 wave grid
  const int lm = lane & 15, kq = lane >> 4;

  // XCD-bijective swizzle: nwg = 1536 = 8 * 192 (divisible by 8 -> simple form).
  const int bid = blockIdx.x;
  const int swz = (bid & 7) * 192 + (bid >> 3);
  const int bm = swz % 64;           // M tile 0..63
  const int bn = swz / 64;           // N tile 0..23 (consecutive ids share B panel)

  // staging: per tile, A = 1024 chunks of 16B (2 instrs x 512 thr), same for B.
  // chunk c -> row = c>>2 (64B rows of BK=32 bf16), col-chunk = c&3.
  const __bf16* pA0 = A + (size_t)(bm * 256 + (tid >> 2)) * DIM + (tid & 3) * 8;
  const __bf16* pA1 = pA0 + (size_t)128 * DIM;
  const __bf16* pB0 = W + (size_t)(bn * 256 + (tid >> 2)) * DIM + (tid & 3) * 8;
  const __bf16* pB1 = pB0 + (size_t)128 * DIM;

#define STAGE(tt)                                                   \
  {                                                                 \
    __bf16* db = lds + ((tt) & 3) * 16384 + w * 512;                \
    gload16(pA0 + (tt) * BK, db);                                   \
    gload16(pA1 + (tt) * BK, db + 4096);                            \
    gload16(pB0 + (tt) * BK, db + 8192);                            \
    gload16(pB1 + (tt) * BK, db + 12288);                           \
  }

  f32x4 acc[8][4];
#pragma unroll
  for (int i = 0; i < 8; ++i)
#pragma unroll
    for (int j = 0; j < 4; ++j) acc[i][j] = (f32x4){0.f, 0.f, 0.f, 0.f};

  // prologue: 3 tiles in flight (12 per-wave loads)
  STAGE(0);
  STAGE(1);
  STAGE(2);

  for (int t = 0; t < KTILES; ++t) {
    // Wait for tile t only: tiles t..t+2 outstanding (12 loads), leave 8 in flight.
    if (t < KTILES - 2) {
      asm volatile("s_waitcnt vmcnt(8)" ::: "memory");
    } else if (t == KTILES - 2) {
      asm volatile("s_waitcnt vmcnt(4)" ::: "memory");
    } else {
      asm volatile("s_waitcnt vmcnt(0)" ::: "memory");
    }
    __builtin_amdgcn_s_barrier();      // all waves: tile t resident, tile t-1 reads done
    asm volatile("" ::: "memory");     // keep LDS reads below the barrier
    __builtin_amdgcn_sched_barrier(0);

    if (t <= KTILES - 4) STAGE(t + 3); // overwrites buf[(t-1)&3]: safe after barrier

    const __bf16* baseA = lds + (t & 3) * 16384 + (wm * 128 + lm) * BK + kq * 8;
    const __bf16* baseB = lds + (t & 3) * 16384 + 8192 + (wn * 64 + lm) * BK + kq * 8;
    bf16x8 af[8], bf[4];
#pragma unroll
    for (int i = 0; i < 8; ++i) af[i] = *(const bf16x8*)(baseA + i * 512);
#pragma unroll
    for (int j = 0; j < 4; ++j) bf[j] = *(const bf16x8*)(baseB + j * 512);

    __builtin_amdgcn_s_setprio(1);
#pragma unroll
    for (int i = 0; i < 8; ++i)
#pragma unroll
      for (int j = 0; j < 4; ++j)
        acc[i][j] = __builtin_amdgcn_mfma_f32_16x16x32_bf16(af[i], bf[j], acc[i][j], 0, 0, 0);
    __builtin_amdgcn_s_setprio(0);
  }
#undef STAGE

  // epilogue: C/D layout col=lane&15, row=(lane>>4)*4+reg (verified m89/m91)
  const int mat = bn >> 3;  // 8 N-tiles per matrix (2048/256)
  const float* bias = (mat == 0) ? bq : (mat == 1) ? bk : bv;
  const int colb = bn * 256 + wn * 64 + lm;
  const int rowb = bm * 256 + wm * 128 + kq * 4;
#pragma unroll
  for (int i = 0; i < 8; ++i) {
#pragma unroll
    for (int j = 0; j < 4; ++j) {
      const int col = colb + j * 16;
      const float bs = bias[col & (DIM - 1)];
#pragma unroll
      for (int r = 0; r < 4; ++r) {
        const int row = rowb + i * 16 + r;
        C[(size_t)row * NTOT + col] = f2bf(acc[i][j][r] + bs);
      }
    }
  }
}

__device__ __forceinline__ void unpack8(uint4 v, float* f) {
  f[0] = __uint_as_float(v.x << 16);
  f[1] = __uint_as_float(v.x & 0xffff0000u);
  f[2] = __uint_as_float(v.y << 16);
  f[3] = __uint_as_float(v.y & 0xffff0000u);
  f[4] = __uint_as_float(v.z << 16);
  f[5] = __uint_as_float(v.z & 0xffff0000u);
  f[6] = __uint_as_float(v.w << 16);
  f[7] = __uint_as_float(v.w & 0xffff0000u);
}

// One WAVE per token. Lane = s*16+g: group g (0..15), dim-quarter s (0..3, 32 dims).
// K|V (8KB contiguous) staged into a private LDS region via global_load_lds;
// no cross-wave sharing -> no barriers, just own-wave vmcnt(0).
// Scores: per-lane partial dot over 32 dims, 2x shfl_xor (16,32) to finish.
__global__ __launch_bounds__(256) void attn_kernel(const u16* __restrict__ qkv,
                                                   float* __restrict__ out) {
  __shared__ __bf16 kv[4][4096];  // per-wave 8KB: k[16][128] then v[16][128]

  const int tid = threadIdx.x;
  const int lane = tid & 63;
  const int w = tid >> 6;
  const int token = blockIdx.x * 4 + w;
  const int g = lane & 15, s = lane >> 4;

  const __bf16* base = (const __bf16*)(qkv) + (size_t)token * NTOT;

  // stage k|v: 8 instrs x (64 lanes x 16B) = 8KB, fully coalesced
  const __bf16* kvsrc = base + DIM;
#pragma unroll
  for (int i = 0; i < 8; ++i)
    gload16(kvsrc + i * 512 + lane * 8, (__bf16*)kv[w] + i * 512);

  // q fragment for (g, s): 32 dims -> registers (overlaps with K/V staging)
  float qf[32];
  const __bf16* qsrc = base + g * DG + s * 32;
#pragma unroll
  for (int j = 0; j < 4; ++j) {
    uint4 qc = *(const uint4*)(qsrc + j * 8);
    unpack8(qc, qf + j * 8);
  }

  asm volatile("s_waitcnt vmcnt(0)" ::: "memory");  // own stages done; region private

  // scores: sc[h] = q[g]:32dims . k[h]:32dims, then 4-lane reduce over s
  float sc[16];
  const __bf16* kl = (const __bf16*)kv[w] + s * 32;
#pragma unroll 4
  for (int h = 0; h < 16; ++h) {
    const uint4* kr = (const uint4*)(kl + h * DG);
    float a = 0.f;
#pragma unroll
    for (int j = 0; j < 4; ++j) {
      float kf[8];
      unpack8(kr[j], kf);
#pragma unroll
      for (int e = 0; e < 8; ++e) a = fmaf(qf[j * 8 + e], kf[e], a);
    }
    sc[h] = a;
  }
#pragma unroll
  for (int h = 0; h < 16; ++h) {
    float v = sc[h];
    v += __shfl_xor(v, 16);
    v += __shfl_xor(v, 32);
    sc[h] = v;  // all 4 s-lanes now hold the full dot
  }

  const float scale = 0.08838834764831845f;  // 1/sqrt(128)
  float mx = sc[0] * scale;
#pragma unroll
  for (int h = 1; h < 16; ++h) mx = fmaxf(mx, sc[h] * scale);
  float p[16], sum = 0.f;
#pragma unroll
  for (int h = 0; h < 16; ++h) {
    p[h] = __expf(sc[h] * scale - mx);
    sum += p[h];
  }
  const float inv = 1.f / sum;
#pragma unroll
  for (int h = 0; h < 16; ++h) p[h] *= inv;

  // out[g][s*32 .. +32] = sum_h p[h] * v[h][dims]
  float o[32];
#pragma unroll
  for (int e = 0; e < 32; ++e) o[e] = 0.f;
  const __bf16* vl = (const __bf16*)kv[w] + 2048 + s * 32;
#pragma unroll 4
  for (int h = 0; h < 16; ++h) {
    const uint4* vr = (const uint4*)(vl + h * DG);
    const float ph = p[h];
#pragma unroll
    for (int j = 0; j < 4; ++j) {
      float vf[8];
      unpack8(vr[j], vf);
#pragma unroll
      for (int e = 0; e < 8; ++e) o[j * 8 + e] = fmaf(ph, vf[e], o[j * 8 + e]);
    }
  }

  float* ob = out + (size_t)token * DIM + g * DG + s * 32;
#pragma unroll
  for (int j = 0; j < 8; ++j) {
    float4 v4 = {o[j * 4], o[j * 4 + 1], o[j * 4 + 2], o[j * 4 + 3]};
    ((float4*)ob)[j] = v4;
  }
}

extern "C" void kernel_launch(void* const* d_in, const int* in_sizes, int n_in,
                              void* d_out, int out_size, void* d_ws, size_t ws_size,
                              hipStream_t stream) {
  const float* x  = (const float*)d_in[0];
  const float* Wq = (const float*)d_in[1];
  const float* bq = (const float*)d_in[2];
  const float* Wk = (const float*)d_in[3];
  const float* bk = (const float*)d_in[4];
  const float* Wv = (const float*)d_in[5];
  const float* bv = (const float*)d_in[6];
  float* out = (float*)d_out;

  const int M = in_sizes[0] / DIM;  // 16384 tokens

  // ws layout: x_bf16 [M*2048] | W_bf16 [3*2048*2048] | qkv_bf16 [M*6144]
  u16* xb  = (u16*)d_ws;
  u16* wb  = xb + (size_t)M * DIM;
  u16* qkv = wb + (size_t)3 * DIM * DIM;

  const int n4x = (M * DIM) / 4;
  cvt_kernel<<<dim3((n4x + 255) / 256), 256, 0, stream>>>(x, xb, n4x);
  const int n4w = (DIM * DIM) / 4;
  cvtW_kernel<<<dim3((n4w + 255) / 256, 3), 256, 0, stream>>>(Wq, Wk, Wv, wb, n4w);

  gemm_qkv<<<dim3((M / 256) * (NTOT / 256)), 512, 0, stream>>>(
      (const __bf16*)xb, (const __bf16*)wb, bq, bk, bv, qkv);

  attn_kernel<<<dim3(M / 4), 256, 0, stream>>>(qkv, out);
}

// Round 3
// 714.860 us; speedup vs baseline: 1.3648x; 1.0153x over previous
//
#include <hip/hip_runtime.h>

// GQA group-attention: q/k/v GEMMs (bf16 MFMA) + per-token 16x16 group attention.
// R2': identical to R2 (bench infra failed; no kernel signal). GEMM + LDS
//     XOR-swizzle (T2) on top of R1's counted-vmcnt 4-deep pipeline.
//     slot' = slot ^ ((row>>1)&3) applied as pre-swizzled global SOURCE (linear
//     global_load_lds dest, rule #21) + swizzled ds_read address. Kills the
//     4-way-per-issue-group bank conflict (3.78e7 measured) on the
//     barrier->MFMA critical path. attn unchanged (isolate one change).

#define DIM 2048
#define NTOT 6144   // 3*DIM, concatenated q|k|v per token
#define DG 128      // per-group dim
#define NG 16       // groups
#define BK 32
#define KTILES (DIM / BK)   // 64

typedef __bf16 bf16x8 __attribute__((ext_vector_type(8)));
typedef float f32x4 __attribute__((ext_vector_type(4)));
typedef unsigned short u16;
typedef unsigned int u32;

__device__ __forceinline__ u16 f2bf(float f) {
  u32 u = __float_as_uint(f);
  u = (u + 0x7fffu + ((u >> 16) & 1u)) >> 16;  // RNE
  return (u16)u;
}

__device__ __forceinline__ void gload16(const __bf16* g, __bf16* l) {
  // async global->LDS DMA, 16B per lane; LDS dest = wave-uniform base + lane*16,
  // global src is per-lane.
  __builtin_amdgcn_global_load_lds(
      (__attribute__((address_space(1))) void*)(void*)g,
      (__attribute__((address_space(3))) void*)l, 16, 0, 0);
}

__global__ __launch_bounds__(256) void cvt_kernel(const float* __restrict__ src,
                                                  u16* __restrict__ dst, int n4) {
  int i = blockIdx.x * 256 + threadIdx.x;
  if (i >= n4) return;
  float4 f = ((const float4*)src)[i];
  ushort4 o;
  o.x = f2bf(f.x); o.y = f2bf(f.y); o.z = f2bf(f.z); o.w = f2bf(f.w);
  ((ushort4*)dst)[i] = o;
}

__global__ __launch_bounds__(256) void cvtW_kernel(const float* __restrict__ wq,
                                                   const float* __restrict__ wk,
                                                   const float* __restrict__ wv,
                                                   u16* __restrict__ dst, int n4each) {
  int m = blockIdx.y;
  const float* s = (m == 0) ? wq : (m == 1) ? wk : wv;
  int i = blockIdx.x * 256 + threadIdx.x;
  if (i >= n4each) return;
  float4 f = ((const float4*)s)[i];
  ushort4 o;
  o.x = f2bf(f.x); o.y = f2bf(f.y); o.z = f2bf(f.z); o.w = f2bf(f.w);
  ((ushort4*)dst)[(size_t)m * n4each + i] = o;
}

// C[row][col] = A[row][:] . W[col][:] + bias, stored bf16.
// A: [M][2048] bf16, W: [6144][2048] bf16 (Wq|Wk|Wv rows), C: [M][6144] bf16.
// 256x256 tile, 8 waves (2x4), per-wave 128x64 output (acc[8][4]).
// LDS: 4 circular buffers x (A 16KB + B 16KB) = 128 KB.
// LDS tile layout [row][32] bf16 (4 slots of 16B per 64B row), XOR-swizzled:
//   LDS(row, slot) holds global (row, slot ^ ((row>>1)&3)).
__global__ __launch_bounds__(512, 1) void gemm_qkv(const __bf16* __restrict__ A,
                                                   const __bf16* __restrict__ W,
                                                   const float* __restrict__ bq,
                                                   const float* __restrict__ bk,
                                                   const float* __restrict__ bv,
                                                   u16* __restrict__ C) {
  __shared__ __bf16 lds[4 * 16384];  // 128 KB: buf q at q*16384, A then B(+8192)

  const int tid = threadIdx.x;       // 0..511
  const int lane = tid & 63;
  const int w = tid >> 6;            // wave 0..7
  const int wm = w >> 2, wn = w & 3; // 2 x 4 wave grid
  const int lm = lane & 15, kq = lane >> 4;

  // XCD-bijective swizzle: nwg = 1536 = 8 * 192 (divisible by 8 -> simple form).
  const int bid = blockIdx.x;
  const int swz = (bid & 7) * 192 + (bid >> 3);
  const int bm = swz % 64;           // M tile 0..63
  const int bn = swz / 64;           // N tile 0..23 (consecutive ids share B panel)

  // staging: per tile, A = 1024 chunks of 16B (2 instrs x 512 thr), same for B.
  // chunk c = j*512 + tid -> row = c>>2, slot = c&3; SOURCE slot pre-swizzled:
  // slot_g = (c&3) ^ ((c>>3)&3)  (row>>1 = c>>3; +128-row offset is ^0 mod 4).
  const int slotg = ((tid & 3) ^ ((tid >> 3) & 3)) * 8;  // elements
  const __bf16* pA0 = A + (size_t)(bm * 256 + (tid >> 2)) * DIM + slotg;
  const __bf16* pA1 = pA0 + (size_t)128 * DIM;
  const __bf16* pB0 = W + (size_t)(bn * 256 + (tid >> 2)) * DIM + slotg;
  const __bf16* pB1 = pB0 + (size_t)128 * DIM;

#define STAGE(tt)                                                   \
  {                                                                 \
    __bf16* db = lds + ((tt) & 3) * 16384 + w * 512;                \
    gload16(pA0 + (tt) * BK, db);                                   \
    gload16(pA1 + (tt) * BK, db + 4096);                            \
    gload16(pB0 + (tt) * BK, db + 8192);                            \
    gload16(pB1 + (tt) * BK, db + 12288);                           \
  }

  f32x4 acc[8][4];
#pragma unroll
  for (int i = 0; i < 8; ++i)
#pragma unroll
    for (int j = 0; j < 4; ++j) acc[i][j] = (f32x4){0.f, 0.f, 0.f, 0.f};

  // prologue: 3 tiles in flight (12 per-wave loads)
  STAGE(0);
  STAGE(1);
  STAGE(2);

  // Read fragment bases, swizzled: slot' = kq ^ ((row>>1)&3); row = wm*128+i*16+lm
  // (A) or wn*64+j*16+lm (B) -> (row>>1)&3 == (lm>>1)&3 in both (other terms are
  // multiples of 8 after >>1). i/j advance whole 16-row blocks -> XOR term const.
  const int sw = (kq ^ ((lm >> 1) & 3)) * 8;  // elements
  const int aoff = (wm * 128 + lm) * BK + sw;
  const int boff = 8192 + (wn * 64 + lm) * BK + sw;

  for (int t = 0; t < KTILES; ++t) {
    // Wait for tile t only: tiles t..t+2 outstanding (12 loads), leave 8 in flight.
    if (t < KTILES - 2) {
      asm volatile("s_waitcnt vmcnt(8)" ::: "memory");
    } else if (t == KTILES - 2) {
      asm volatile("s_waitcnt vmcnt(4)" ::: "memory");
    } else {
      asm volatile("s_waitcnt vmcnt(0)" ::: "memory");
    }
    __builtin_amdgcn_s_barrier();      // all waves: tile t resident, tile t-1 reads done
    asm volatile("" ::: "memory");     // keep LDS reads below the barrier
    __builtin_amdgcn_sched_barrier(0);

    if (t <= KTILES - 4) STAGE(t + 3); // overwrites buf[(t-1)&3]: safe after barrier

    const __bf16* baseA = lds + (t & 3) * 16384 + aoff;
    const __bf16* baseB = lds + (t & 3) * 16384 + boff;
    bf16x8 af[8], bf[4];
#pragma unroll
    for (int i = 0; i < 8; ++i) af[i] = *(const bf16x8*)(baseA + i * 512);
#pragma unroll
    for (int j = 0; j < 4; ++j) bf[j] = *(const bf16x8*)(baseB + j * 512);

    __builtin_amdgcn_s_setprio(1);
#pragma unroll
    for (int i = 0; i < 8; ++i)
#pragma unroll
      for (int j = 0; j < 4; ++j)
        acc[i][j] = __builtin_amdgcn_mfma_f32_16x16x32_bf16(af[i], bf[j], acc[i][j], 0, 0, 0);
    __builtin_amdgcn_s_setprio(0);
  }
#undef STAGE

  // epilogue: C/D layout col=lane&15, row=(lane>>4)*4+reg (verified m89/m91)
  const int mat = bn >> 3;  // 8 N-tiles per matrix (2048/256)
  const float* bias = (mat == 0) ? bq : (mat == 1) ? bk : bv;
  const int colb = bn * 256 + wn * 64 + lm;
  const int rowb = bm * 256 + wm * 128 + kq * 4;
#pragma unroll
  for (int i = 0; i < 8; ++i) {
#pragma unroll
    for (int j = 0; j < 4; ++j) {
      const int col = colb + j * 16;
      const float bs = bias[col & (DIM - 1)];
#pragma unroll
      for (int r = 0; r < 4; ++r) {
        const int row = rowb + i * 16 + r;
        C[(size_t)row * NTOT + col] = f2bf(acc[i][j][r] + bs);
      }
    }
  }
}

__device__ __forceinline__ void unpack8(uint4 v, float* f) {
  f[0] = __uint_as_float(v.x << 16);
  f[1] = __uint_as_float(v.x & 0xffff0000u);
  f[2] = __uint_as_float(v.y << 16);
  f[3] = __uint_as_float(v.y & 0xffff0000u);
  f[4] = __uint_as_float(v.z << 16);
  f[5] = __uint_as_float(v.z & 0xffff0000u);
  f[6] = __uint_as_float(v.w << 16);
  f[7] = __uint_as_float(v.w & 0xffff0000u);
}

// One WAVE per token. Lane = s*16+g: group g (0..15), dim-quarter s (0..3, 32 dims).
// K|V (8KB contiguous) staged into a private LDS region via global_load_lds;
// no cross-wave sharing -> no barriers, just own-wave vmcnt(0).
__global__ __launch_bounds__(256) void attn_kernel(const u16* __restrict__ qkv,
                                                   float* __restrict__ out) {
  __shared__ __bf16 kv[4][4096];  // per-wave 8KB: k[16][128] then v[16][128]

  const int tid = threadIdx.x;
  const int lane = tid & 63;
  const int w = tid >> 6;
  const int token = blockIdx.x * 4 + w;
  const int g = lane & 15, s = lane >> 4;

  const __bf16* base = (const __bf16*)(qkv) + (size_t)token * NTOT;

  // stage k|v: 8 instrs x (64 lanes x 16B) = 8KB, fully coalesced
  const __bf16* kvsrc = base + DIM;
#pragma unroll
  for (int i = 0; i < 8; ++i)
    gload16(kvsrc + i * 512 + lane * 8, (__bf16*)kv[w] + i * 512);

  // q fragment for (g, s): 32 dims -> registers (overlaps with K/V staging)
  float qf[32];
  const __bf16* qsrc = base + g * DG + s * 32;
#pragma unroll
  for (int j = 0; j < 4; ++j) {
    uint4 qc = *(const uint4*)(qsrc + j * 8);
    unpack8(qc, qf + j * 8);
  }

  asm volatile("s_waitcnt vmcnt(0)" ::: "memory");  // own stages done; region private

  // scores: sc[h] = q[g]:32dims . k[h]:32dims, then 4-lane reduce over s
  float sc[16];
  const __bf16* kl = (const __bf16*)kv[w] + s * 32;
#pragma unroll 4
  for (int h = 0; h < 16; ++h) {
    const uint4* kr = (const uint4*)(kl + h * DG);
    float a = 0.f;
#pragma unroll
    for (int j = 0; j < 4; ++j) {
      float kf[8];
      unpack8(kr[j], kf);
#pragma unroll
      for (int e = 0; e < 8; ++e) a = fmaf(qf[j * 8 + e], kf[e], a);
    }
    sc[h] = a;
  }
#pragma unroll
  for (int h = 0; h < 16; ++h) {
    float v = sc[h];
    v += __shfl_xor(v, 16);
    v += __shfl_xor(v, 32);
    sc[h] = v;  // all 4 s-lanes now hold the full dot
  }

  const float scale = 0.08838834764831845f;  // 1/sqrt(128)
  float mx = sc[0] * scale;
#pragma unroll
  for (int h = 1; h < 16; ++h) mx = fmaxf(mx, sc[h] * scale);
  float p[16], sum = 0.f;
#pragma unroll
  for (int h = 0; h < 16; ++h) {
    p[h] = __expf(sc[h] * scale - mx);
    sum += p[h];
  }
  const float inv = 1.f / sum;
#pragma unroll
  for (int h = 0; h < 16; ++h) p[h] *= inv;

  // out[g][s*32 .. +32] = sum_h p[h] * v[h][dims]
  float o[32];
#pragma unroll
  for (int e = 0; e < 32; ++e) o[e] = 0.f;
  const __bf16* vl = (const __bf16*)kv[w] + 2048 + s * 32;
#pragma unroll 4
  for (int h = 0; h < 16; ++h) {
    const uint4* vr = (const uint4*)(vl + h * DG);
    const float ph = p[h];
#pragma unroll
    for (int j = 0; j < 4; ++j) {
      float vf[8];
      unpack8(vr[j], vf);
#pragma unroll
      for (int e = 0; e < 8; ++e) o[j * 8 + e] = fmaf(ph, vf[e], o[j * 8 + e]);
    }
  }

  float* ob = out + (size_t)token * DIM + g * DG + s * 32;
#pragma unroll
  for (int j = 0; j < 8; ++j) {
    float4 v4 = {o[j * 4], o[j * 4 + 1], o[j * 4 + 2], o[j * 4 + 3]};
    ((float4*)ob)[j] = v4;
  }
}

extern "C" void kernel_launch(void* const* d_in, const int* in_sizes, int n_in,
                              void* d_out, int out_size, void* d_ws, size_t ws_size,
                              hipStream_t stream) {
  const float* x  = (const float*)d_in[0];
  const float* Wq = (const float*)d_in[1];
  const float* bq = (const float*)d_in[2];
  const float* Wk = (const float*)d_in[3];
  const float* bk = (const float*)d_in[4];
  const float* Wv = (const float*)d_in[5];
  const float* bv = (const float*)d_in[6];
  float* out = (float*)d_out;

  const int M = in_sizes[0] / DIM;  // 16384 tokens

  // ws layout: x_bf16 [M*2048] | W_bf16 [3*2048*2048] | qkv_bf16 [M*6144]
  u16* xb  = (u16*)d_ws;
  u16* wb  = xb + (size_t)M * DIM;
  u16* qkv = wb + (size_t)3 * DIM * DIM;

  const int n4x = (M * DIM) / 4;
  cvt_kernel<<<dim3((n4x + 255) / 256), 256, 0, stream>>>(x, xb, n4x);
  const int n4w = (DIM * DIM) / 4;
  cvtW_kernel<<<dim3((n4w + 255) / 256, 3), 256, 0, stream>>>(Wq, Wk, Wv, wb, n4w);

  gemm_qkv<<<dim3((M / 256) * (NTOT / 256)), 512, 0, stream>>>(
      (const __bf16*)xb, (const __bf16*)wb, bq, bk, bv, qkv);

  attn_kernel<<<dim3(M / 4), 256, 0, stream>>>(qkv, out);
}